// Round 2
// baseline (81.046 us; speedup 1.0000x reference)
//
#include <hip/hip_runtime.h>

// NALU B=1024, I=512, O=512 — SINGLE fused dispatch, fp16 MFMA 16x16x32.
//   w1 = tanh(w_hat)*sigmoid(m_hat); a = x@w1; s = log(max(|x|,eps))@w1
//   m1 = exp(min(s,20)); out = g1*a + (1-g1)*m1*clip(ms,-1,1)
// s ~ N(-143,11^2) => m1 underflows to 0; guarded exactly: any s > -80
// takes a cold path computing the true sign-product from wh/mh.
//
// R1 lesson: harness poisons the 256MB workspace EVERY iteration (41us fill,
// also evicts all of L2+L3 -> every input read is HBM-cold). R1's fused
// kernel ran 1 block/CU with a __syncthreads between a cold-HBM phase-1 and
// the GEMM -> whole-CU barrier stalls with nothing to overlap.
// R2: same fusion, but 256-thr blocks / tile 32b x 32o / grid (16,32) =
// 512 blocks = 2 blocks/CU: the co-resident block's GEMM hides the other's
// phase-1 latency + barrier (R0-main's proven occupancy geometry, which had
// no barrier stall). K-loop unroll capped at 4 to bound VGPR live ranges.
// Frag layouts (learn_hip-verified): A[m=lane&15][k=(lane>>4)*8+j],
// B[k=(lane>>4)*8+j][n=lane&15], D[m=(lane>>4)*4+reg][n=lane&15].

#define O_N 512
#define I_N 512
#define B_N 1024

typedef _Float16 f16;
typedef _Float16 f16x8 __attribute__((ext_vector_type(8)));
typedef float f32x4 __attribute__((ext_vector_type(4)));

__device__ __forceinline__ float fast_sigmoid(float v) {
    return 1.0f / (1.0f + __expf(-v));
}
__device__ __forceinline__ float fast_tanh(float v) {
    return 1.0f - 2.0f / (1.0f + __expf(2.0f * v));   // exact at both tails
}

__global__ __launch_bounds__(256, 2)
void nalu_fused_kernel(const float* __restrict__ x,
                       const float* __restrict__ wh,
                       const float* __restrict__ mh,
                       const float* __restrict__ g,
                       float* __restrict__ out) {
    // B frags for this block: f = tn*16 + kb; 32 frags x 64 lanes x 16B = 32KB
    __shared__ f16x8 bsh[32 * 64];

    const int lane  = threadIdx.x & 63;
    const int w     = threadIdx.x >> 6;     // 0..3
    const int o_blk = blockIdx.x * 32;
    const int b_blk = blockIdx.y * 32;

    // ---- phase 1: cooperative B-frag prep (w1 = tanh(wh)*sigmoid(mh))
    {
        const int rk = (lane >> 4) * 8;     // frag-k base within the 32-k tile
        const int cn = lane & 15;
#pragma unroll 2
        for (int q = 0; q < 8; ++q) {
            const int f     = w * 8 + q;    // 0..31, wave w owns 8 frags
            const int kb_f  = f & 15;
            const int n     = o_blk + (f >> 4) * 16 + cn;
            const int kbase = kb_f * 32 + rk;
            const float* wp = wh + kbase * O_N + n;
            const float* mp = mh + kbase * O_N + n;
            f16x8 bf;
#pragma unroll
            for (int j = 0; j < 8; ++j) {
                const float wv = wp[j * O_N];
                const float mv = mp[j * O_N];
                bf[j] = (f16)(fast_tanh(wv) * fast_sigmoid(mv));
            }
            bsh[f * 64 + lane] = bf;        // lane-contiguous ds_write_b128
        }
    }
    __syncthreads();

    // ---- phase 2: dual GEMM (a-path and s-path share the B frag)
    const int tm = w & 1;                   // 2 b-subtiles of 16
    const int tn = w >> 1;                  // 2 o-subtiles of 16
    const int b0 = b_blk + tm * 16;
    const int o0 = o_blk + tn * 16;

    const int m    = b0 + (lane & 15);
    const int k0l  = (lane >> 4) * 8;
    const float* xrow = x + m * I_N + k0l;
    const f16x8* bsw  = bsh + tn * 16 * 64 + lane;

    f32x4 ca = {0.f, 0.f, 0.f, 0.f}, cs = ca;
#pragma unroll 4
    for (int kb = 0; kb < 16; ++kb) {
        const f16x8 bf = bsw[kb * 64];                       // ds_read_b128
        const float4 q0 = *(const float4*)(xrow + kb * 32);  // k-contiguous
        const float4 q1 = *(const float4*)(xrow + kb * 32 + 4);
        const float vx[8] = {q0.x, q0.y, q0.z, q0.w, q1.x, q1.y, q1.z, q1.w};
        f16x8 ax, al;
#pragma unroll
        for (int j = 0; j < 8; ++j) {
            ax[j] = (f16)vx[j];
            al[j] = (f16)__logf(fmaxf(fabsf(vx[j]), 1e-7f));
        }
        ca = __builtin_amdgcn_mfma_f32_16x16x32_f16(ax, bf, ca, 0, 0, 0);
        cs = __builtin_amdgcn_mfma_f32_16x16x32_f16(al, bf, cs, 0, 0, 0);
    }

    // ---- epilogue: D[m=(lane>>4)*4+r][n=lane&15]
    const int col = lane & 15;
    const int rq  = (lane >> 4) * 4;
    const int o   = o0 + col;
    const float g1  = fast_sigmoid(g[o]);
    const float omg = 1.0f - g1;
#pragma unroll
    for (int r = 0; r < 4; ++r) {
        const int b = b0 + rq + r;
        const float sv = cs[r];
        const float m1 = __expf(fminf(sv, 20.0f));
        float msv = 1.0f;
        if (sv > -80.0f) {                  // cold path (expected never): exact ms
            float p = 1.0f;
            for (int i = 0; i < I_N; ++i) {
                // ws_oi[o][i] = |w1.flat[o*I+i]| = |w1[row=o][col=i]|
                const float wv = fabsf(fast_tanh(wh[o * I_N + i]) *
                                       fast_sigmoid(mh[o * I_N + i]));
                const float xv = x[b * I_N + i];
                const float sg = (xv > 0.f) ? 1.f : ((xv < 0.f) ? -1.f : 0.f);
                p *= sg * wv + (1.0f - wv);
            }
            msv = fminf(fmaxf(p, -1.0f), 1.0f);
        }
        out[b * O_N + o] = g1 * ca[r] + omg * m1 * msv;
    }
}

extern "C" void kernel_launch(void* const* d_in, const int* in_sizes, int n_in,
                              void* d_out, int out_size, void* d_ws, size_t ws_size,
                              hipStream_t stream) {
    const float* x  = (const float*)d_in[0];   // [B, I]
    const float* wh = (const float*)d_in[1];   // [I, O]
    const float* mh = (const float*)d_in[2];   // [I, O]
    const float* g  = (const float*)d_in[3];   // [O]
    float* out = (float*)d_out;                // [B, O] fp32
    (void)d_ws; (void)ws_size;                 // workspace intentionally unused

    nalu_fused_kernel<<<dim3(16, 32), 256, 0, stream>>>(x, wh, mh, g, out);
}

// Round 3
// 75.099 us; speedup vs baseline: 1.0792x; 1.0792x over previous
//
#include <hip/hip_runtime.h>

// NALU B=1024, I=512, O=512 — two dispatches, fp16 MFMA 16x16x32.
//   w1 = tanh(w_hat)*sigmoid(m_hat); a = x@w1; s = log(max(|x|,eps))@w1
//   m1 = exp(min(s,20)); out = g1*a + (1-g1)*m1*clip(ms,-1,1)
// s ~ N(-143,11^2) => m1 underflows to 0; guarded exactly: any s > -80
// takes a cold path computing the true sign-product from wh/mh.
//
// Session history:
//   R0 (2-dispatch, A+B prep): 68.2us  <- reproducible best
//   R1 (fused, 16x w1 redundancy): 73.8us
//   R2 (fused, 32x w1 redundancy): 81.0us
// Regression scales with in-kernel w1-recompute redundancy => the
// coalesced redundancy-free B-prep dispatch is worth more than the
// launch it costs. R3: keep R0's B-prep verbatim; drop the A-prep half
// (main builds A-frags on the fly from contiguous float4 reads of x —
// no transpose/LDS/barrier needed, same bytes as the apx reads it
// replaces, removes a 2MB ws write + read-back and 256 prep blocks).
//
// Frag layouts (learn_hip-verified): A[m=lane&15][k=(lane>>4)*8+j],
// B[k=(lane>>4)*8+j][n=lane&15], D[m=(lane>>4)*4+reg][n=lane&15].

#define O_N 512
#define I_N 512
#define B_N 1024

typedef _Float16 f16;
typedef _Float16 f16x8 __attribute__((ext_vector_type(8)));
typedef float f32x4 __attribute__((ext_vector_type(4)));

__device__ __forceinline__ float fast_sigmoid(float v) {
    return 1.0f / (1.0f + __expf(-v));
}
__device__ __forceinline__ float fast_tanh(float v) {
    return 1.0f - 2.0f / (1.0f + __expf(2.0f * v));   // exact at both tails
}

// ---- prep: 128 blocks, B frags only (each block: 32k x 64n tile of w1)
__global__ __launch_bounds__(256) void prep_kernel(const float* __restrict__ wh,
                                                   const float* __restrict__ mh,
                                                   f16x8* __restrict__ bp) {
    const int tid = threadIdx.x;
    __shared__ f16 lt[32][72];          // w1 tile [k][n]; 72 = 144B row (16B-mult)
    const int kb = blockIdx.x >> 3;     // 0..15  (k-tile of 32)
    const int nb = blockIdx.x & 7;      // 0..7   (n-tile of 64)
    // read phase: row r (32 rows), 8 consecutive n per thread -> coalesced
    const int r  = tid >> 3;
    const int c0 = (tid & 7) * 8;
    const int base = (kb * 32 + r) * O_N + nb * 64 + c0;
    const float4* w4 = (const float4*)(wh + base);
    const float4* m4 = (const float4*)(mh + base);
    const float4 wa = w4[0], wb = w4[1], ma = m4[0], mb = m4[1];
    f16x8 row;
    row[0] = (f16)(fast_tanh(wa.x) * fast_sigmoid(ma.x));
    row[1] = (f16)(fast_tanh(wa.y) * fast_sigmoid(ma.y));
    row[2] = (f16)(fast_tanh(wa.z) * fast_sigmoid(ma.z));
    row[3] = (f16)(fast_tanh(wa.w) * fast_sigmoid(ma.w));
    row[4] = (f16)(fast_tanh(wb.x) * fast_sigmoid(mb.x));
    row[5] = (f16)(fast_tanh(wb.y) * fast_sigmoid(mb.y));
    row[6] = (f16)(fast_tanh(wb.z) * fast_sigmoid(mb.z));
    row[7] = (f16)(fast_tanh(wb.w) * fast_sigmoid(mb.w));
    *(f16x8*)&lt[r][c0] = row;          // one aligned ds_write_b128
    __syncthreads();
    // frag phase: 256 frags, one per thread
    const int fl  = tid & 63;
    const int tnl = tid >> 6;           // 0..3 local n-subtile
    const int nl  = tnl * 16 + (fl & 15);
    const int k0  = (fl >> 4) * 8;
    f16x8 bf;
#pragma unroll
    for (int j = 0; j < 8; ++j) bf[j] = lt[k0 + j][nl];
    const int tn_g = nb * 4 + tnl;      // global n-tile (0..31)
    bp[tn_g * 1024 + kb * 64 + fl] = bf;
}

// ---- main: grid (16,32), 256 thr / 4 waves; block 32b x 32o, wave 16b x 16o
//      A-frags built on the fly from x (k-runs contiguous); no LDS, no barrier.
__global__ __launch_bounds__(256) void nalu_mfma_kernel(const f16x8* __restrict__ bp,
                                                        const float* __restrict__ g,
                                                        const float* __restrict__ x,
                                                        const float* __restrict__ wh,
                                                        const float* __restrict__ mh,
                                                        float* __restrict__ out) {
    const int lane = threadIdx.x & 63;
    const int w    = threadIdx.x >> 6;
    const int b0   = blockIdx.y * 32 + (w & 1) * 16;
    const int o0   = blockIdx.x * 32 + (w >> 1) * 16;
    const int tn   = o0 >> 4;

    f32x4 ca = {0.f, 0.f, 0.f, 0.f}, cs = ca;

    const int m      = b0 + (lane & 15);
    const float* xrow = x + m * I_N + (lane >> 4) * 8;
    const f16x8* pbp  = bp + tn * 1024 + lane;

#pragma unroll 8
    for (int tk = 0; tk < 16; ++tk) {
        const f16x8 bf = pbp[tk * 64];                       // 16B coalesced
        const float4 q0 = *(const float4*)(xrow + tk * 32);  // k-contiguous
        const float4 q1 = *(const float4*)(xrow + tk * 32 + 4);
        const float vx[8] = {q0.x, q0.y, q0.z, q0.w, q1.x, q1.y, q1.z, q1.w};
        f16x8 ax, al;
#pragma unroll
        for (int j = 0; j < 8; ++j) {
            ax[j] = (f16)vx[j];
            al[j] = (f16)__logf(fmaxf(fabsf(vx[j]), 1e-7f));
        }
        ca = __builtin_amdgcn_mfma_f32_16x16x32_f16(ax, bf, ca, 0, 0, 0);
        cs = __builtin_amdgcn_mfma_f32_16x16x32_f16(al, bf, cs, 0, 0, 0);
    }

    // epilogue: D[m=(lane>>4)*4+r][n=lane&15]
    const int col = lane & 15;
    const int rq  = (lane >> 4) * 4;
    const int o   = o0 + col;
    const float g1  = fast_sigmoid(g[o]);
    const float omg = 1.0f - g1;
#pragma unroll
    for (int r = 0; r < 4; ++r) {
        const int b = b0 + rq + r;
        const float sv = cs[r];
        const float m1 = __expf(fminf(sv, 20.0f));
        float msv = 1.0f;
        if (sv > -80.0f) {                  // cold path (expected never): exact ms
            float p = 1.0f;
            for (int i = 0; i < I_N; ++i) {
                // ws_oi[o][i] = |w1.flat[o*I+i]| = |w1[row=o][col=i]|
                const float wv = fabsf(fast_tanh(wh[o * I_N + i]) *
                                       fast_sigmoid(mh[o * I_N + i]));
                const float xv = x[b * I_N + i];
                const float sg = (xv > 0.f) ? 1.f : ((xv < 0.f) ? -1.f : 0.f);
                p *= sg * wv + (1.0f - wv);
            }
            msv = fminf(fmaxf(p, -1.0f), 1.0f);
        }
        out[b * O_N + o] = g1 * ca[r] + omg * m1 * msv;
    }
}

extern "C" void kernel_launch(void* const* d_in, const int* in_sizes, int n_in,
                              void* d_out, int out_size, void* d_ws, size_t ws_size,
                              hipStream_t stream) {
    const float* x  = (const float*)d_in[0];   // [B, I]
    const float* wh = (const float*)d_in[1];   // [I, O]
    const float* mh = (const float*)d_in[2];   // [I, O]
    const float* g  = (const float*)d_in[3];   // [O]
    float* out = (float*)d_out;                // [B, O] fp32

    f16x8* bp = (f16x8*)d_ws;                  // 512 KB (32*16*64 frags)

    prep_kernel<<<128, 256, 0, stream>>>(wh, mh, bp);
    nalu_mfma_kernel<<<dim3(16, 32), 256, 0, stream>>>(bp, g, x, wh, mh, out);
}